// Round 2
// baseline (8789.493 us; speedup 1.0000x reference)
//
#include <hip/hip_runtime.h>
#include <math.h>

typedef unsigned long long ull;

// LTC liquid scan — batch-amortized GEMM decomposition.
// Round-5 change: TWO independent pipelines per CU. Blocks shrink to 256
// threads / BT=4 batches (inner structure unchanged: per thread 2 batches x
// 4 neurons x 32 k = 256 FMA/unfold, wv = 128 floats). Grid 512 = 32 batch-
// tiles x 16 neuron-tiles, 2 blocks/CU (LDS 54.4 KB -> exactly 2 fit; 8
// waves/CU; VGPR ~112 << 256 limit). Rationale: VALUBusy was 28.5% with one
// barrier-locked block per CU — ~71% of CU time idle in the per-unfold
// serial chain (GEMV -> reduce -> IC publish -> spin-wait ~600-900 cy).
// Co-resident blocks are from different batch-tile groups and drift
// independently, so one block's mailbox wait overlaps the other's GEMV.
// Mailbox IC traffic unchanged (512 x 16 KB = 8 MB/unfold).
// Spin safety: 2/CU x 256 CU = 512 = grid => all resident, fence-free
// versioned mailbox (RELAXED agent atomics, exact version match) as before.
//
// Round-4 (kept): XOR-swizzle all hot LDS rows at float4 granularity
// (slot = g ^ ((g>>3)&7)); conflicts 1.67e9 -> 3.1e8.

#define NN 512
#define FF 256
#define KK 6
#define BB 128
#define TT 256
#define BT 4         // batches per tile
#define NTL 32       // neurons per tile

#define XROW 512     // xsh row pitch (dwords); conflicts handled by swizzle
#define IPITCH 260   // = 65 float4
#define WIPITCH 260  // = 65 float4
#define PPITCH 17

#define DOT4(a, v) ((a).x * (v).x + (a).y * (v).y + (a).z * (v).z + (a).w * (v).w)

__global__ __launch_bounds__(256, 2) void liquid_kernel(
    const float* __restrict__ I,     // [B][T][F]
    const float* __restrict__ DT,    // [B][T]
    const float* __restrict__ Wrec,  // [N][N]
    const float* __restrict__ Win,   // [N][F]
    const float* __restrict__ bv, const float* __restrict__ Av,
    const float* __restrict__ tauv,
    ull* __restrict__ mbx,           // [32 bt][2 slot][4 b][512 n] versioned
    float* __restrict__ out)         // [B][T][N]
{
  __shared__ __align__(16) float lds[13592];  // 54.4 KB -> 2 blocks/CU
  float* xsh = lds;                   // [4][512]  x_{jj-1}, swizzled f4 groups
  float* iro = lds + BT * XROW;       // [4][260]  input rows, swizzled
  float* wi  = iro + BT * IPITCH;     // [32][260] W_in slice, swizzled
  float* par = wi + NTL * WIPITCH;    // [128][17] k-chunk partials
  float* dts = par + 128 * PPITCH;    // [4] dt/K per batch

  const int blk = blockIdx.x;
  const int bt  = blk >> 4;          // batch tile (32)
  const int nt  = blk & 15;          // neuron tile (16)
  const int tid = threadIdx.x;
  const int kc  = tid & 15;          // k-chunk (32 k each)
  const int nq  = (tid >> 4) & 7;    // n-quad (4 n each)
  const int db  = tid >> 7;          // b-pair (2 b each), {0,1}
  const int n0g = nt * NTL;          // global n base of this tile

  // ---- W_rec slice into VGPRs: wv[r][j] = Wrec[n0g+4nq+r][32kc+4j .. +3] ----
  float4 wv[4][8];
  #pragma unroll
  for (int r = 0; r < 4; ++r) {
    const float* wr = Wrec + (size_t)(n0g + nq * 4 + r) * NN + kc * 32;
    #pragma unroll
    for (int j = 0; j < 8; ++j) wv[r][j] = *(const float4*)(wr + 4 * j);
  }
  // ---- W_in slice into LDS (swizzled slot per float4 group) ----
  for (int idx = tid; idx < NTL * FF; idx += 256) {
    const int n = idx >> 8, f = idx & 255;
    const int g = f >> 2, gs = g ^ ((g >> 3) & 7);
    wi[n * WIPITCH + gs * 4 + (f & 3)] = Win[(size_t)(n0g + n) * FF + f];
  }
  // ---- per-neuron params + swizzled xo index for reduction threads ----
  float rA = 0.f, rIT = 0.f, rB = 0.f;
  int swn = 0;
  if (tid < 128) {
    const int rn = tid & 31;
    const int n = n0g + rn;
    rA = Av[n]; rIT = 1.0f / tauv[n]; rB = bv[n];
    const int gg = (n0g >> 2) + (rn >> 2);          // group of neuron n
    swn = ((gg ^ (nt & 7)) << 2) | (rn & 3);        // (gg>>3)&7 == nt&7
  }
  for (int idx = tid; idx < BT * XROW; idx += 256) xsh[idx] = 0.f;  // x0=0

  // ---- thread-constant swizzled addressing (hoisted out of the t-loop) ----
  const int lid = tid & 63;                         // lane in wave
  const int sb  = tid >> 6;                         // wave id / staging row (4)
  const int gsi = lid ^ ((lid >> 3) & 7);           // iro stage-write slot
  const int sxr = (lid >> 2) & 7;                   // xsh stage swizzle sel
  const int sx  = kc & 7;                           // xsh GEMV read sel
  const int gb  = (kc * 4) ^ ((kc >> 1) & 7);       // wi/iro read slot base
  const float4* xq0 = (const float4*)xsh + (db * 2) * 128 + kc * 8;
  const float4* xq1 = xq0 + 128;
  const float4* iq0 = (const float4*)iro + (db * 2) * 65;
  const float4* iq1 = iq0 + 65;
  const float4* wq  = (const float4*)wi + (nq * 4) * 65;
  float4* xw = (float4*)xsh + sb * 128;             // stage-write row
  __syncthreads();

  int jj = 0;
  #pragma unroll 1
  for (int t = 0; t < TT; ++t) {
    // ---- stage input rows (swizzled) + dt ----
    ((float4*)iro)[sb * 65 + gsi] =
        *(const float4*)&I[((size_t)(bt * BT + sb) * TT + t) * FF + lid * 4];
    if (tid < BT) dts[tid] = DT[(size_t)(bt * BT + tid) * TT + t] * (1.0f / KK);
    __syncthreads();

    // ---- input GEMV partials: inp[b][n] over f in [16kc,16kc+16) ----
    {
      float ai0[4] = {0.f, 0.f, 0.f, 0.f}, ai1[4] = {0.f, 0.f, 0.f, 0.f};
      #pragma unroll
      for (int j2 = 0; j2 < 4; ++j2) {
        const int gg = gb ^ j2;                     // swizzled slot
        float4 w0 = wq[0 * 65 + gg];
        float4 w1 = wq[1 * 65 + gg];
        float4 w2 = wq[2 * 65 + gg];
        float4 w3 = wq[3 * 65 + gg];
        float4 xa = iq0[gg];
        float4 xb = iq1[gg];
        ai0[0] += DOT4(w0, xa); ai0[1] += DOT4(w1, xa);
        ai0[2] += DOT4(w2, xa); ai0[3] += DOT4(w3, xa);
        ai1[0] += DOT4(w0, xb); ai1[1] += DOT4(w1, xb);
        ai1[2] += DOT4(w2, xb); ai1[3] += DOT4(w3, xb);
      }
      #pragma unroll
      for (int r = 0; r < 4; ++r) {
        par[((db * 2 + 0) * NTL + nq * 4 + r) * PPITCH + kc] = ai0[r];
        par[((db * 2 + 1) * NTL + nq * 4 + r) * PPITCH + kc] = ai1[r];
      }
    }
    __syncthreads();
    float rInp = 0.f;
    if (tid < 128) {
      float s = rB;
      #pragma unroll
      for (int c = 0; c < 16; ++c) s += par[tid * PPITCH + c];
      rInp = s;
    }
    __syncthreads();  // par free for unfold reuse

    // ---- K unfolds ----
    #pragma unroll 1
    for (int kk = 0; kk < KK; ++kk) {
      ++jj;  // producing x_jj; consuming x_{jj-1}

      // stage x_{jj-1}[4][512] from mailbox (skip jj==1: x0=0 already in xsh)
      if (jj > 1) {
        const ull* src = mbx + (((size_t)bt * 2 + ((jj - 1) & 1)) << 11);
        const ull* p = src + sb * 512 + lid * 8;
        ull v[8];
        #pragma unroll
        for (int i = 0; i < 8; ++i)
          v[i] = __hip_atomic_load(p + i, __ATOMIC_RELAXED, __HIP_MEMORY_SCOPE_AGENT);
        #pragma unroll
        for (int i = 0; i < 8; ++i)
          while ((unsigned)(v[i] >> 32) != (unsigned)(jj - 1)) {
            __builtin_amdgcn_s_sleep(1);
            v[i] = __hip_atomic_load(p + i, __ATOMIC_RELAXED, __HIP_MEMORY_SCOPE_AGENT);
          }
        float4 fa, fb;
        fa.x = __uint_as_float((unsigned)v[0]);
        fa.y = __uint_as_float((unsigned)v[1]);
        fa.z = __uint_as_float((unsigned)v[2]);
        fa.w = __uint_as_float((unsigned)v[3]);
        fb.x = __uint_as_float((unsigned)v[4]);
        fb.y = __uint_as_float((unsigned)v[5]);
        fb.z = __uint_as_float((unsigned)v[6]);
        fb.w = __uint_as_float((unsigned)v[7]);
        const int g0 = 2 * lid;                     // logical groups 2l, 2l+1
        xw[g0 ^ sxr] = fa;
        xw[(g0 + 1) ^ sxr] = fb;
      }
      __syncthreads();

      // GEMV: acc[b][n] partial over k in [32kc, 32kc+32), W from VGPRs.
      // slot (j ^ sx) holds logical group j -> pairs with wv[r][j].
      {
        float acc0[4] = {0.f, 0.f, 0.f, 0.f}, acc1[4] = {0.f, 0.f, 0.f, 0.f};
        #pragma unroll
        for (int j = 0; j < 8; ++j) {
          float4 xv = xq0[j ^ sx];
          acc0[0] += DOT4(wv[0][j], xv); acc0[1] += DOT4(wv[1][j], xv);
          acc0[2] += DOT4(wv[2][j], xv); acc0[3] += DOT4(wv[3][j], xv);
        }
        #pragma unroll
        for (int j = 0; j < 8; ++j) {
          float4 xv = xq1[j ^ sx];
          acc1[0] += DOT4(wv[0][j], xv); acc1[1] += DOT4(wv[1][j], xv);
          acc1[2] += DOT4(wv[2][j], xv); acc1[3] += DOT4(wv[3][j], xv);
        }
        #pragma unroll
        for (int r = 0; r < 4; ++r) {
          par[((db * 2 + 0) * NTL + nq * 4 + r) * PPITCH + kc] = acc0[r];
          par[((db * 2 + 1) * NTL + nq * 4 + r) * PPITCH + kc] = acc1[r];
        }
      }
      __syncthreads();

      // reduce + nonlinearity + publish (+ output on last unfold)
      if (tid < 128) {
        float arg = rInp;
        #pragma unroll
        for (int c = 0; c < 16; ++c) arg += par[tid * PPITCH + c];
        const int rb = tid >> 5, rn = tid & 31;
        float f   = tanhf(arg);
        float dtk = dts[rb];
        float xo  = xsh[rb * XROW + swn];
        float xn  = fmaf(dtk * f, rA, xo) / fmaf(dtk, rIT + f, 1.0f);
        ull w = ((ull)(unsigned)jj << 32) | (ull)__float_as_uint(xn);
        __hip_atomic_store(mbx + (((size_t)bt * 2 + (jj & 1)) << 11) + rb * 512 + n0g + rn,
                           w, __ATOMIC_RELAXED, __HIP_MEMORY_SCOPE_AGENT);
        if (kk == KK - 1)
          out[((size_t)(bt * BT + rb) * TT + t) * NN + n0g + rn] = xn;
      }
      __syncthreads();  // xsh/par reads done before next stage overwrites
    }
  }
}

extern "C" void kernel_launch(void* const* d_in, const int* in_sizes, int n_in,
                              void* d_out, int out_size, void* d_ws, size_t ws_size,
                              hipStream_t stream) {
  const float* I    = (const float*)d_in[0];
  const float* DT   = (const float*)d_in[1];
  const float* Wrec = (const float*)d_in[2];
  const float* Win  = (const float*)d_in[3];
  const float* bv   = (const float*)d_in[4];
  const float* Av   = (const float*)d_in[5];
  const float* tauv = (const float*)d_in[6];
  float* out = (float*)d_out;
  ull* mbx = (ull*)d_ws;  // 32*2*4*512*8 B = 1 MB

  liquid_kernel<<<512, 256, 0, stream>>>(I, DT, Wrec, Win, bv, Av, tauv, mbx, out);
}

// Round 3
// 6881.399 us; speedup vs baseline: 1.2773x; 1.2773x over previous
//
#include <hip/hip_runtime.h>
#include <math.h>

typedef unsigned long long ull;

// LTC liquid scan — batch-amortized GEMM decomposition.
// Grid 256 = 16 batch-tiles x 16 neuron-tiles; block 512 threads, 1 block/CU
// (grid==CU count => co-residency => spin-wait is safe).
// W_rec slice [32 n][512 k] = 64 KB in VGPRs (128/thread). W_in slice in LDS.
// Per-unfold cross-block state exchange x[8][512] via fence-free versioned
// 8-byte mailbox (RELAXED agent atomics only). 2 slots (jj parity).
//
// Round-6 change: BATCHED mailbox re-poll. The old staging loop re-polled
// its 8 entries one-at-a-time in a dependent chain — 8 serial agent-scope
// load round-trips (~900 cy each) = ~7.2K of the measured ~8K idle cycles
// per unfold. Now a pending-mask sweep reissues all stale loads as
// independent loads (one RT per sweep). Predicted idle -> ~1.5-2.5K/unfold.
// (Round-5's 2-blocks/CU experiment regressed 7.1->8.8 ms: co-resident
// blocks convoy instead of drifting; reverted to 1 block/CU, BT=8.)
//
// Round-4 (kept): XOR-swizzle all hot LDS rows at float4 granularity
// (slot = g ^ ((g>>3)&7)); conflicts 1.67e9 -> 3.1e8.

#define NN 512
#define FF 256
#define KK 6
#define BB 128
#define TT 256
#define BT 8         // batches per tile
#define NTL 32       // neurons per tile

#define XROW 512     // xsh row pitch (dwords); conflicts handled by swizzle
#define IPITCH 260   // = 65 float4
#define WIPITCH 260  // = 65 float4
#define PPITCH 17

#define DOT4(a, v) ((a).x * (v).x + (a).y * (v).y + (a).z * (v).z + (a).w * (v).w)

__global__ __launch_bounds__(512, 2) void liquid_kernel(
    const float* __restrict__ I,     // [B][T][F]
    const float* __restrict__ DT,    // [B][T]
    const float* __restrict__ Wrec,  // [N][N]
    const float* __restrict__ Win,   // [N][F]
    const float* __restrict__ bv, const float* __restrict__ Av,
    const float* __restrict__ tauv,
    ull* __restrict__ mbx,           // [16 bt][2 slot][8 b][512 n] versioned
    float* __restrict__ out)         // [B][T][N]
{
  __shared__ __align__(16) float lds[18856];  // 75.4 KB -> 1 block/CU
  float* xsh = lds;                   // [8][512]  x_{jj-1}, swizzled f4 groups
  float* iro = lds + BT * XROW;       // [8][260]  input rows, swizzled
  float* wi  = iro + BT * IPITCH;     // [32][260] W_in slice, swizzled
  float* par = wi + NTL * WIPITCH;    // [256][17] k-chunk partials
  float* dts = par + 256 * PPITCH;    // [8] dt/K per batch

  const int blk = blockIdx.x;
  const int bt  = blk >> 4;          // batch tile
  const int nt  = blk & 15;          // neuron tile
  const int tid = threadIdx.x;
  const int kc  = tid & 15;          // k-chunk (32 k each)
  const int nq  = (tid >> 4) & 7;    // n-quad (4 n each)
  const int db  = tid >> 7;          // b-pair (2 b each)
  const int n0g = nt * NTL;          // global n base of this tile

  // ---- W_rec slice into VGPRs: wv[r][j] = Wrec[n0g+4nq+r][32kc+4j .. +3] ----
  float4 wv[4][8];
  #pragma unroll
  for (int r = 0; r < 4; ++r) {
    const float* wr = Wrec + (size_t)(n0g + nq * 4 + r) * NN + kc * 32;
    #pragma unroll
    for (int j = 0; j < 8; ++j) wv[r][j] = *(const float4*)(wr + 4 * j);
  }
  // ---- W_in slice into LDS (swizzled slot per float4 group) ----
  for (int idx = tid; idx < NTL * FF; idx += 512) {
    const int n = idx >> 8, f = idx & 255;
    const int g = f >> 2, gs = g ^ ((g >> 3) & 7);
    wi[n * WIPITCH + gs * 4 + (f & 3)] = Win[(size_t)(n0g + n) * FF + f];
  }
  // ---- per-neuron params + swizzled xo index for reduction threads ----
  float rA = 0.f, rIT = 0.f, rB = 0.f;
  int swn = 0;
  if (tid < 256) {
    const int rn = tid & 31;
    const int n = n0g + rn;
    rA = Av[n]; rIT = 1.0f / tauv[n]; rB = bv[n];
    const int gg = (n0g >> 2) + (rn >> 2);          // group of neuron n
    swn = ((gg ^ (nt & 7)) << 2) | (rn & 3);        // (gg>>3)&7 == nt&7
  }
  for (int idx = tid; idx < BT * XROW; idx += 512) xsh[idx] = 0.f;  // x0=0

  // ---- thread-constant swizzled addressing (hoisted out of the t-loop) ----
  const int lid = tid & 63;                         // lane in wave
  const int sb  = tid >> 6;                         // wave id / staging row
  const int gsi = lid ^ ((lid >> 3) & 7);           // iro stage-write slot
  const int sxr = (lid >> 2) & 7;                   // xsh stage swizzle sel
  const int sx  = kc & 7;                           // xsh GEMV read sel
  const int gb  = (kc * 4) ^ ((kc >> 1) & 7);       // wi/iro read slot base
  const float4* xq0 = (const float4*)xsh + (db * 2) * 128 + kc * 8;
  const float4* xq1 = xq0 + 128;
  const float4* iq0 = (const float4*)iro + (db * 2) * 65;
  const float4* iq1 = iq0 + 65;
  const float4* wq  = (const float4*)wi + (nq * 4) * 65;
  float4* xw = (float4*)xsh + sb * 128;             // stage-write row
  __syncthreads();

  int jj = 0;
  #pragma unroll 1
  for (int t = 0; t < TT; ++t) {
    // ---- stage input rows (swizzled) + dt ----
    ((float4*)iro)[sb * 65 + gsi] =
        *(const float4*)&I[((size_t)(bt * BT + sb) * TT + t) * FF + lid * 4];
    if (tid < BT) dts[tid] = DT[(size_t)(bt * BT + tid) * TT + t] * (1.0f / KK);
    __syncthreads();

    // ---- input GEMV partials: inp[b][n] over f in [16kc,16kc+16) ----
    {
      float ai0[4] = {0.f, 0.f, 0.f, 0.f}, ai1[4] = {0.f, 0.f, 0.f, 0.f};
      #pragma unroll
      for (int j2 = 0; j2 < 4; ++j2) {
        const int gg = gb ^ j2;                     // swizzled slot
        float4 w0 = wq[0 * 65 + gg];
        float4 w1 = wq[1 * 65 + gg];
        float4 w2 = wq[2 * 65 + gg];
        float4 w3 = wq[3 * 65 + gg];
        float4 xa = iq0[gg];
        float4 xb = iq1[gg];
        ai0[0] += DOT4(w0, xa); ai0[1] += DOT4(w1, xa);
        ai0[2] += DOT4(w2, xa); ai0[3] += DOT4(w3, xa);
        ai1[0] += DOT4(w0, xb); ai1[1] += DOT4(w1, xb);
        ai1[2] += DOT4(w2, xb); ai1[3] += DOT4(w3, xb);
      }
      #pragma unroll
      for (int r = 0; r < 4; ++r) {
        par[((db * 2 + 0) * NTL + nq * 4 + r) * PPITCH + kc] = ai0[r];
        par[((db * 2 + 1) * NTL + nq * 4 + r) * PPITCH + kc] = ai1[r];
      }
    }
    __syncthreads();
    float rInp = 0.f;
    if (tid < 256) {
      float s = rB;
      #pragma unroll
      for (int c = 0; c < 16; ++c) s += par[tid * PPITCH + c];
      rInp = s;
    }
    __syncthreads();  // par free for unfold reuse

    // ---- K unfolds ----
    #pragma unroll 1
    for (int kk = 0; kk < KK; ++kk) {
      ++jj;  // producing x_jj; consuming x_{jj-1}

      // stage x_{jj-1}[8][512] from mailbox (skip jj==1: x0=0 already in xsh)
      if (jj > 1) {
        const ull* src = mbx + (((size_t)bt * 2 + ((jj - 1) & 1)) << 12);
        const ull* p = src + sb * 512 + lid * 8;
        const unsigned want = (unsigned)(jj - 1);
        ull v[8];
        #pragma unroll
        for (int i = 0; i < 8; ++i)
          v[i] = __hip_atomic_load(p + i, __ATOMIC_RELAXED, __HIP_MEMORY_SCOPE_AGENT);
        unsigned pend = 0;
        #pragma unroll
        for (int i = 0; i < 8; ++i)
          if ((unsigned)(v[i] >> 32) != want) pend |= 1u << i;
        // batched re-poll: each sweep re-issues ALL stale loads as
        // independent loads (one RT per sweep, not one RT per entry)
        while (pend) {
          __builtin_amdgcn_s_sleep(1);
          ull w[8];
          #pragma unroll
          for (int i = 0; i < 8; ++i)
            if (pend & (1u << i))
              w[i] = __hip_atomic_load(p + i, __ATOMIC_RELAXED, __HIP_MEMORY_SCOPE_AGENT);
          #pragma unroll
          for (int i = 0; i < 8; ++i)
            if (pend & (1u << i)) {
              if ((unsigned)(w[i] >> 32) == want) {
                v[i] = w[i];
                pend &= ~(1u << i);
              }
            }
        }
        float4 fa, fb;
        fa.x = __uint_as_float((unsigned)v[0]);
        fa.y = __uint_as_float((unsigned)v[1]);
        fa.z = __uint_as_float((unsigned)v[2]);
        fa.w = __uint_as_float((unsigned)v[3]);
        fb.x = __uint_as_float((unsigned)v[4]);
        fb.y = __uint_as_float((unsigned)v[5]);
        fb.z = __uint_as_float((unsigned)v[6]);
        fb.w = __uint_as_float((unsigned)v[7]);
        const int g0 = 2 * lid;                     // logical groups 2l, 2l+1
        xw[g0 ^ sxr] = fa;
        xw[(g0 + 1) ^ sxr] = fb;
      }
      __syncthreads();

      // GEMV: acc[b][n] partial over k in [32kc, 32kc+32), W from VGPRs.
      // slot (j ^ sx) holds logical group j -> pairs with wv[r][j].
      {
        float acc0[4] = {0.f, 0.f, 0.f, 0.f}, acc1[4] = {0.f, 0.f, 0.f, 0.f};
        #pragma unroll
        for (int j = 0; j < 8; ++j) {
          float4 xv = xq0[j ^ sx];
          acc0[0] += DOT4(wv[0][j], xv); acc0[1] += DOT4(wv[1][j], xv);
          acc0[2] += DOT4(wv[2][j], xv); acc0[3] += DOT4(wv[3][j], xv);
        }
        #pragma unroll
        for (int j = 0; j < 8; ++j) {
          float4 xv = xq1[j ^ sx];
          acc1[0] += DOT4(wv[0][j], xv); acc1[1] += DOT4(wv[1][j], xv);
          acc1[2] += DOT4(wv[2][j], xv); acc1[3] += DOT4(wv[3][j], xv);
        }
        #pragma unroll
        for (int r = 0; r < 4; ++r) {
          par[((db * 2 + 0) * NTL + nq * 4 + r) * PPITCH + kc] = acc0[r];
          par[((db * 2 + 1) * NTL + nq * 4 + r) * PPITCH + kc] = acc1[r];
        }
      }
      __syncthreads();

      // reduce + nonlinearity + publish (+ output on last unfold)
      if (tid < 256) {
        float arg = rInp;
        #pragma unroll
        for (int c = 0; c < 16; ++c) arg += par[tid * PPITCH + c];
        const int rb = tid >> 5, rn = tid & 31;
        float f   = tanhf(arg);
        float dtk = dts[rb];
        float xo  = xsh[rb * XROW + swn];
        float xn  = fmaf(dtk * f, rA, xo) / fmaf(dtk, rIT + f, 1.0f);
        ull w = ((ull)(unsigned)jj << 32) | (ull)__float_as_uint(xn);
        __hip_atomic_store(mbx + (((size_t)bt * 2 + (jj & 1)) << 12) + rb * 512 + n0g + rn,
                           w, __ATOMIC_RELAXED, __HIP_MEMORY_SCOPE_AGENT);
        if (kk == KK - 1)
          out[((size_t)(bt * BT + rb) * TT + t) * NN + n0g + rn] = xn;
      }
      __syncthreads();  // xsh/par reads done before next stage overwrites
    }
  }
}

extern "C" void kernel_launch(void* const* d_in, const int* in_sizes, int n_in,
                              void* d_out, int out_size, void* d_ws, size_t ws_size,
                              hipStream_t stream) {
  const float* I    = (const float*)d_in[0];
  const float* DT   = (const float*)d_in[1];
  const float* Wrec = (const float*)d_in[2];
  const float* Win  = (const float*)d_in[3];
  const float* bv   = (const float*)d_in[4];
  const float* Av   = (const float*)d_in[5];
  const float* tauv = (const float*)d_in[6];
  float* out = (float*)d_out;
  ull* mbx = (ull*)d_ws;  // 16*2*8*512*8 B = 1 MB

  liquid_kernel<<<256, 512, 0, stream>>>(I, DT, Wrec, Win, bv, Av, tauv, mbx, out);
}

// Round 4
// 3473.501 us; speedup vs baseline: 2.5304x; 1.9811x over previous
//
#include <hip/hip_runtime.h>
#include <math.h>

typedef unsigned long long ull;

// LTC liquid scan — batch-amortized GEMM decomposition.
// Round-7 change: REPARTITION to cut exchange traffic 4x. Books from round-6:
// FETCH 3.29 GB = I(32MB) + ~3.25GB poll loads (each block re-reads the full
// x[BT][512] ~4x per unfold through the agent path); stage wait ~4-6K cy of
// the ~10K cy/unfold. Consumer read volume = grid x BT x 512 x 8B scales with
// BT only — so BT 8->2, NTL 32->128: grid 256 = 64 batch-tiles x 4 neuron-
// tiles, 2 batches x 128 neurons per block. Per-thread work unchanged
// (2b x 4n x 32k = 256 FMA/unfold, wv = 128 floats, thread map (kc, nq0..31)).
// W_in slice [128][256] now in LDS -> 153 KB total (1 block/CU, 8 waves).
// Poll reads 8->2 MB/unfold; peers 16->4 (less skew-max). Publish volume,
// FLOPs, swizzle patterns preserved.
// Round-6 (kept): batched mailbox re-poll sweeps (independent loads per RT).
// Round-4 (kept): XOR-swizzle all hot LDS rows at float4 granularity
// (slot = g ^ ((g>>3)&7)); conflicts 1.67e9 -> 3.1e8.

#define NN 512
#define FF 256
#define KK 6
#define BB 128
#define TT 256
#define BT 2         // batches per tile
#define NTL 128      // neurons per tile

#define XROW 512     // xsh row pitch (dwords); conflicts handled by swizzle
#define IPITCH 260   // = 65 float4
#define WIPITCH 260  // = 65 float4
#define PPITCH 17

#define DOT4(a, v) ((a).x * (v).x + (a).y * (v).y + (a).z * (v).z + (a).w * (v).w)

__global__ __launch_bounds__(512, 2) void liquid_kernel(
    const float* __restrict__ I,     // [B][T][F]
    const float* __restrict__ DT,    // [B][T]
    const float* __restrict__ Wrec,  // [N][N]
    const float* __restrict__ Win,   // [N][F]
    const float* __restrict__ bv, const float* __restrict__ Av,
    const float* __restrict__ tauv,
    ull* __restrict__ mbx,           // [64 bt][2 slot][2 b][512 n] versioned
    float* __restrict__ out)         // [B][T][N]
{
  __shared__ __align__(16) float lds[39178];  // 153.0 KB -> 1 block/CU
  float* xsh = lds;                   // [2][512]  x_{jj-1}, swizzled f4 groups
  float* iro = lds + BT * XROW;       // [2][260]  input rows, swizzled
  float* wi  = iro + BT * IPITCH;     // [128][260] W_in slice, swizzled
  float* par = wi + NTL * WIPITCH;    // [256][17] k-chunk partials
  float* dts = par + 256 * PPITCH;    // [2] dt/K per batch

  const int blk = blockIdx.x;
  const int bt  = blk >> 2;          // batch tile (64)
  const int nt  = blk & 3;           // neuron tile (4)
  const int tid = threadIdx.x;
  const int kc  = tid & 15;          // k-chunk (32 k each)
  const int nq  = tid >> 4;          // n-quad (4 n each), 0..31
  const int n0g = nt * NTL;          // global n base of this tile

  // ---- W_rec slice into VGPRs: wv[r][j] = Wrec[n0g+4nq+r][32kc+4j .. +3] ----
  float4 wv[4][8];
  #pragma unroll
  for (int r = 0; r < 4; ++r) {
    const float* wr = Wrec + (size_t)(n0g + nq * 4 + r) * NN + kc * 32;
    #pragma unroll
    for (int j = 0; j < 8; ++j) wv[r][j] = *(const float4*)(wr + 4 * j);
  }
  // ---- W_in slice into LDS (swizzled slot per float4 group) ----
  for (int idx = tid; idx < NTL * FF; idx += 512) {
    const int n = idx >> 8, f = idx & 255;
    const int g = f >> 2, gs = g ^ ((g >> 3) & 7);
    wi[n * WIPITCH + gs * 4 + (f & 3)] = Win[(size_t)(n0g + n) * FF + f];
  }
  // ---- per-(b,n) params + swizzled xo index for reduction threads ----
  float rA = 0.f, rIT = 0.f, rB = 0.f;
  int swn = 0;
  if (tid < 256) {
    const int rn = tid & 127;                       // local neuron
    const int n = n0g + rn;
    rA = Av[n]; rIT = 1.0f / tauv[n]; rB = bv[n];
    const int gg = n >> 2;                          // global f4 group
    swn = ((gg ^ ((gg >> 3) & 7)) << 2) | (n & 3);
  }
  for (int idx = tid; idx < BT * XROW; idx += 512) xsh[idx] = 0.f;  // x0=0

  // ---- thread-constant swizzled addressing (hoisted out of the t-loop) ----
  const int sx  = kc & 7;                           // xsh GEMV read sel
  const int gb  = (kc * 4) ^ ((kc >> 1) & 7);       // wi/iro read slot base
  const float4* xq0 = (const float4*)xsh + kc * 8;  // batch 0
  const float4* xq1 = xq0 + 128;                    // batch 1
  const float4* iq0 = (const float4*)iro;
  const float4* iq1 = iq0 + 65;
  const float4* wq  = (const float4*)wi + (nq * 4) * 65;
  // stage: thread handles mailbox entries {2tid, 2tid+1} -> (b, n, n+1)
  const int stb = tid >> 8;                         // staging batch row
  const int stn = 2 * (tid & 255);                  // local n (even)
  const int stg = stn >> 2;                         // logical f4 group
  float* stw = xsh + stb * XROW + ((stg ^ ((stg >> 3) & 7)) << 2) + (stn & 3);
  __syncthreads();

  int jj = 0;
  #pragma unroll 1
  for (int t = 0; t < TT; ++t) {
    // ---- stage input rows (swizzled) + dt ----
    if (tid < 2 * 64) {
      const int b = tid >> 6, f4 = tid & 63;
      const int gsi = f4 ^ ((f4 >> 3) & 7);
      ((float4*)iro)[b * 65 + gsi] =
          *(const float4*)&I[((size_t)(bt * BT + b) * TT + t) * FF + f4 * 4];
    }
    if (tid < BT) dts[tid] = DT[(size_t)(bt * BT + tid) * TT + t] * (1.0f / KK);
    __syncthreads();

    // ---- input GEMV partials: inp[b][n] over f in [16kc,16kc+16) ----
    {
      float ai0[4] = {0.f, 0.f, 0.f, 0.f}, ai1[4] = {0.f, 0.f, 0.f, 0.f};
      #pragma unroll
      for (int j2 = 0; j2 < 4; ++j2) {
        const int gg = gb ^ j2;                     // swizzled slot
        float4 w0 = wq[0 * 65 + gg];
        float4 w1 = wq[1 * 65 + gg];
        float4 w2 = wq[2 * 65 + gg];
        float4 w3 = wq[3 * 65 + gg];
        float4 xa = iq0[gg];
        float4 xb = iq1[gg];
        ai0[0] += DOT4(w0, xa); ai0[1] += DOT4(w1, xa);
        ai0[2] += DOT4(w2, xa); ai0[3] += DOT4(w3, xa);
        ai1[0] += DOT4(w0, xb); ai1[1] += DOT4(w1, xb);
        ai1[2] += DOT4(w2, xb); ai1[3] += DOT4(w3, xb);
      }
      #pragma unroll
      for (int r = 0; r < 4; ++r) {
        par[(0 * NTL + nq * 4 + r) * PPITCH + kc] = ai0[r];
        par[(1 * NTL + nq * 4 + r) * PPITCH + kc] = ai1[r];
      }
    }
    __syncthreads();
    float rInp = 0.f;
    if (tid < 256) {
      float s = rB;
      #pragma unroll
      for (int c = 0; c < 16; ++c) s += par[tid * PPITCH + c];
      rInp = s;
    }
    __syncthreads();  // par free for unfold reuse

    // ---- K unfolds ----
    #pragma unroll 1
    for (int kk = 0; kk < KK; ++kk) {
      ++jj;  // producing x_jj; consuming x_{jj-1}

      // stage x_{jj-1}[2][512] from mailbox (skip jj==1: x0=0 already in xsh)
      if (jj > 1) {
        const ull* src = mbx + (((size_t)bt * 2 + ((jj - 1) & 1)) << 10);
        const ull* p = src + 2 * tid;
        const unsigned want = (unsigned)(jj - 1);
        ull v0 = __hip_atomic_load(p,     __ATOMIC_RELAXED, __HIP_MEMORY_SCOPE_AGENT);
        ull v1 = __hip_atomic_load(p + 1, __ATOMIC_RELAXED, __HIP_MEMORY_SCOPE_AGENT);
        while ((unsigned)(v0 >> 32) != want || (unsigned)(v1 >> 32) != want) {
          __builtin_amdgcn_s_sleep(1);
          if ((unsigned)(v0 >> 32) != want)
            v0 = __hip_atomic_load(p,     __ATOMIC_RELAXED, __HIP_MEMORY_SCOPE_AGENT);
          if ((unsigned)(v1 >> 32) != want)
            v1 = __hip_atomic_load(p + 1, __ATOMIC_RELAXED, __HIP_MEMORY_SCOPE_AGENT);
        }
        stw[0] = __uint_as_float((unsigned)v0);
        stw[1] = __uint_as_float((unsigned)v1);
      }
      __syncthreads();

      // GEMV: acc[b][n] partial over k in [32kc, 32kc+32), W from VGPRs.
      // slot (j ^ sx) holds logical group j -> pairs with wv[r][j].
      {
        float acc0[4] = {0.f, 0.f, 0.f, 0.f}, acc1[4] = {0.f, 0.f, 0.f, 0.f};
        #pragma unroll
        for (int j = 0; j < 8; ++j) {
          float4 xv = xq0[j ^ sx];
          acc0[0] += DOT4(wv[0][j], xv); acc0[1] += DOT4(wv[1][j], xv);
          acc0[2] += DOT4(wv[2][j], xv); acc0[3] += DOT4(wv[3][j], xv);
        }
        #pragma unroll
        for (int j = 0; j < 8; ++j) {
          float4 xv = xq1[j ^ sx];
          acc1[0] += DOT4(wv[0][j], xv); acc1[1] += DOT4(wv[1][j], xv);
          acc1[2] += DOT4(wv[2][j], xv); acc1[3] += DOT4(wv[3][j], xv);
        }
        #pragma unroll
        for (int r = 0; r < 4; ++r) {
          par[(0 * NTL + nq * 4 + r) * PPITCH + kc] = acc0[r];
          par[(1 * NTL + nq * 4 + r) * PPITCH + kc] = acc1[r];
        }
      }
      __syncthreads();

      // reduce + nonlinearity + publish (+ output on last unfold)
      if (tid < 256) {
        float arg = rInp;
        #pragma unroll
        for (int c = 0; c < 16; ++c) arg += par[tid * PPITCH + c];
        const int rb = tid >> 7, rn = tid & 127;
        float f   = tanhf(arg);
        float dtk = dts[rb];
        float xo  = xsh[rb * XROW + swn];
        float xn  = fmaf(dtk * f, rA, xo) / fmaf(dtk, rIT + f, 1.0f);
        ull w = ((ull)(unsigned)jj << 32) | (ull)__float_as_uint(xn);
        __hip_atomic_store(mbx + (((size_t)bt * 2 + (jj & 1)) << 10) + rb * 512 + n0g + rn,
                           w, __ATOMIC_RELAXED, __HIP_MEMORY_SCOPE_AGENT);
        if (kk == KK - 1)
          out[((size_t)(bt * BT + rb) * TT + t) * NN + n0g + rn] = xn;
      }
      __syncthreads();  // xsh/par reads done before next stage overwrites
    }
  }
}

extern "C" void kernel_launch(void* const* d_in, const int* in_sizes, int n_in,
                              void* d_out, int out_size, void* d_ws, size_t ws_size,
                              hipStream_t stream) {
  const float* I    = (const float*)d_in[0];
  const float* DT   = (const float*)d_in[1];
  const float* Wrec = (const float*)d_in[2];
  const float* Win  = (const float*)d_in[3];
  const float* bv   = (const float*)d_in[4];
  const float* Av   = (const float*)d_in[5];
  const float* tauv = (const float*)d_in[6];
  float* out = (float*)d_out;
  ull* mbx = (ull*)d_ws;  // 64*2*2*512*8 B = 1 MB

  liquid_kernel<<<256, 512, 0, stream>>>(I, DT, Wrec, Win, bv, Av, tauv, mbx, out);
}